// Round 6
// baseline (654.971 us; speedup 1.0000x reference)
//
#include <hip/hip_runtime.h>
#include <hip/hip_bf16.h>
#include <math.h>

#define N_MET 20000
#define N_RXN 50000
#define NEDGE 1000000
#define D 128
#define DH 64
#define NTILE ((NEDGE + 127) >> 7)   // 7813

typedef __attribute__((ext_vector_type(8))) short short8;   // 8 bf16 raw bits
typedef __attribute__((ext_vector_type(4))) float f32x4;

__device__ __forceinline__ unsigned short f2bf(float x){
    __hip_bfloat16 b = __float2bfloat16(x);
    return *reinterpret_cast<unsigned short*>(&b);
}
// monotone float<->uint key for atomicMax on floats (key 0 < any finite float's key)
__device__ __forceinline__ unsigned fkey(float x){
    unsigned u = __float_as_uint(x);
    return (u & 0x80000000u) ? ~u : (u | 0x80000000u);
}
__device__ __forceinline__ float fkey_inv(unsigned k){
    unsigned u = (k & 0x80000000u) ? (k ^ 0x80000000u) : ~k;
    return __uint_as_float(u);
}

// ---- fused converts + int64/int32 layout detect ----
#define NB_F ((N_MET*D/4 + 255)/256)   // 2500
#define NB_WT ((D*D + 255)/256)        // 64
#define NB_W1 ((D*DH + 255)/256)       // 32
__global__ __launch_bounds__(256) void cvt_all_kernel(
    const float* __restrict__ feats, const float* __restrict__ Wt,
    const float* __restrict__ W1, const unsigned* __restrict__ he,
    unsigned short* __restrict__ feats_bf, unsigned short* __restrict__ WtT_bf,
    unsigned short* __restrict__ W1T_bf, int* __restrict__ flag)
{
    int b = blockIdx.x;
    if (b < NB_F){
        int i = b*256 + threadIdx.x;
        if (i < N_MET*D/4){
            float4 v = ((const float4*)feats)[i];
            ushort4 o;
            o.x = f2bf(v.x); o.y = f2bf(v.y); o.z = f2bf(v.z); o.w = f2bf(v.w);
            ((ushort4*)feats_bf)[i] = o;
        }
    } else if (b < NB_F + NB_WT){
        int i = (b - NB_F)*256 + threadIdx.x;         // WtT[c*D + k] = Wt[k*D + c]
        if (i < D*D){ int c = i >> 7, k = i & 127; WtT_bf[i] = f2bf(Wt[k*D + c]); }
    } else if (b < NB_F + NB_WT + NB_W1){
        int i = (b - NB_F - NB_WT)*256 + threadIdx.x; // W1T[c*D + k] = W1[k*DH + c]
        if (i < DH*D){ int c = i >> 7, k = i & 127; W1T_bf[i] = f2bf(W1[k*DH + c]); }
    } else {
        if (threadIdx.x == 0){
            int is64 = 1;
            for (int i = 0; i < 64; ++i)
                if (he[2*i + 1] != 0u){ is64 = 0; break; }
            *flag = is64;
        }
    }
}

// ---- Kernel 1: gate via MFMA, direct global A-loads, NO per-tile barriers ----
__global__ __launch_bounds__(512) void gate_kernel(
    const unsigned short* __restrict__ feats_bf, const int* __restrict__ he,
    const unsigned short* __restrict__ W1T_bf, const float* __restrict__ b1,
    const float* __restrict__ W2, const float* __restrict__ b2,
    float* __restrict__ gate, int* __restrict__ count, unsigned* __restrict__ gmaxkey,
    const int* __restrict__ flag)
{
    __shared__ __align__(16) unsigned short W1s[64*136];

    const int tid = threadIdx.x;
    const int stride = (*flag) ? 2 : 1;

    for (int i = tid; i < 64*16; i += 512){          // stage W1T once
        int c = i >> 4, ch = i & 15;
        *(short8*)&W1s[c*136 + ch*8] = *(const short8*)&W1T_bf[c*128 + ch*8];
    }
    __syncthreads();

    const int lane = tid & 63;
    const int wave = tid >> 6;
    const int erow = lane & 15;
    const int kgrp = lane >> 4;

    float b1c[4], w2c[4];
    #pragma unroll
    for (int cf = 0; cf < 4; ++cf){
        int c = cf*16 + erow;
        b1c[cf] = b1[c]; w2c[cf] = W2[c];
    }
    const float b2v = b2[0];

    for (int tile = blockIdx.x; tile < NTILE; tile += gridDim.x){
        const long base = (long)tile * 128;
        if (tid < 128){                              // histogram
            long e = base + tid;
            if (e < NEDGE) atomicAdd(&count[he[(size_t)(NEDGE + e) * stride]], 1);
        }
        // direct A-load: this lane's edge row
        long ea = base + wave*16 + erow;
        long ec = (ea < NEDGE) ? ea : (NEDGE-1);
        int m = he[(size_t)ec * stride];
        const unsigned short* arow = feats_bf + (size_t)m * D;

        f32x4 acc[4];
        #pragma unroll
        for (int cf = 0; cf < 4; ++cf) acc[cf] = (f32x4){0.f,0.f,0.f,0.f};
        #pragma unroll
        for (int ks = 0; ks < 4; ++ks){
            short8 a = *(const short8*)(arow + ks*32 + kgrp*8);
            #pragma unroll
            for (int cf = 0; cf < 4; ++cf){
                short8 b = *(const short8*)&W1s[(cf*16 + erow)*136 + ks*32 + kgrp*8];
                acc[cf] = __builtin_amdgcn_mfma_f32_16x16x32_bf16(a, b, acc[cf], 0, 0, 0);
            }
        }

        float p[4] = {0.f,0.f,0.f,0.f};
        #pragma unroll
        for (int cf = 0; cf < 4; ++cf){
            #pragma unroll
            for (int r = 0; r < 4; ++r)
                p[r] += fmaxf(acc[cf][r] + b1c[cf], 0.f) * w2c[cf];
        }
        #pragma unroll
        for (int off = 1; off < 16; off <<= 1){
            #pragma unroll
            for (int r = 0; r < 4; ++r) p[r] += __shfl_xor(p[r], off);
        }
        if (erow == 0){
            #pragma unroll
            for (int r = 0; r < 4; ++r){
                long e = base + wave*16 + kgrp*4 + r;
                if (e < NEDGE){
                    float g = p[r] + b2v;
                    gate[e] = g;
                    int rx = he[(size_t)(NEDGE + e) * stride];
                    atomicMax(&gmaxkey[rx], fkey(g));
                }
            }
        }
    }
}

// ---- Kernel 2: scan via wave shfl -> offsets, cursor ----
__global__ __launch_bounds__(1024) void scan_kernel(
    const int* __restrict__ count, int* __restrict__ offsets, int* __restrict__ cursor)
{
    __shared__ int wsum[16];
    __shared__ int sbase;
    const int tid = threadIdx.x, lane = tid & 63, wid = tid >> 6;
    if (tid == 0) sbase = 0;
    __syncthreads();
    for (int start = 0; start < N_RXN; start += 1024){
        int idx = start + tid;
        int v = (idx < N_RXN) ? count[idx] : 0;
        int x = v;
        #pragma unroll
        for (int off = 1; off < 64; off <<= 1){
            int t = __shfl_up(x, off);
            if (lane >= off) x += t;
        }
        if (lane == 63) wsum[wid] = x;
        __syncthreads();
        if (wid == 0){
            int s = (lane < 16) ? wsum[lane] : 0;
            #pragma unroll
            for (int off = 1; off < 16; off <<= 1){
                int t = __shfl_up(s, off);
                if (lane >= off) s += t;
            }
            if (lane < 16) wsum[lane] = s;
        }
        __syncthreads();
        int wbase = (wid == 0) ? 0 : wsum[wid-1];
        int excl = sbase + wbase + x - v;
        if (idx < N_RXN){ offsets[idx] = excl; cursor[idx] = excl; }
        __syncthreads();
        if (tid == 0) sbase += wsum[15];
        __syncthreads();
    }
    if (tid == 0) offsets[N_RXN] = sbase;
}

// ---- Kernel 3: counting-sort reorder, fused exp + denom atomic ----
__global__ __launch_bounds__(256) void reorder_kernel(
    const int* __restrict__ he, const float* __restrict__ gate,
    const unsigned* __restrict__ gmaxkey, int* __restrict__ cursor,
    uint2* __restrict__ sorted_pe, float* __restrict__ denom,
    const int* __restrict__ flag)
{
    int e = blockIdx.x*256 + threadIdx.x;
    if (e >= NEDGE) return;
    int stride = (*flag) ? 2 : 1;
    int m = he[(size_t)e * stride];
    int r = he[(size_t)(NEDGE + e) * stride];
    float ex = expf(gate[e] - fkey_inv(gmaxkey[r]));
    int pos = atomicAdd(&cursor[r], 1);
    uint2 pe; pe.x = ((unsigned)r << 15) | (unsigned)m; pe.y = __float_as_uint(ex);
    sorted_pe[pos] = pe;
    atomicAdd(&denom[r], ex);
}

// ---- Kernel 4: transform MFMA (direct A) + full-tile run-merged reduce ----
// Interior runs (not touching local edge 0/127) -> exactly-once plain store.
// Boundary runs -> atomicAdd. 3 barriers/tile.
__global__ __launch_bounds__(512) void scatter_kernel(
    const unsigned short* __restrict__ feats_bf, const uint2* __restrict__ sorted_pe,
    const float* __restrict__ denom, const unsigned short* __restrict__ WtT_bf,
    const float* __restrict__ bt, float* __restrict__ Z)
{
    __shared__ __align__(16) unsigned short Wts[128*136];   // 34816 B
    __shared__ float Ls[128*132];                           // 67584 B
    __shared__ int   mets[128];
    __shared__ int   rxns[128];
    __shared__ float als[128];

    const int tid = threadIdx.x;
    for (int i = tid; i < 128*16; i += 512){         // stage WtT once
        int c = i >> 4, ch = i & 15;
        *(short8*)&Wts[c*136 + ch*8] = *(const short8*)&WtT_bf[c*128 + ch*8];
    }
    const int lane = tid & 63;
    const int wave = tid >> 6;
    const int erow = lane & 15;
    const int kgrp = lane >> 4;

    float btc[8];
    #pragma unroll
    for (int cf = 0; cf < 8; ++cf) btc[cf] = bt[cf*16 + erow];
    __syncthreads();

    for (int tile = blockIdx.x; tile < NTILE; tile += gridDim.x){
        const long base = (long)tile * 128;
        if (tid < 128){
            long p = base + tid;
            unsigned px = 0xFFFFFFFFu; float a = 0.f;
            if (p < NEDGE){
                uint2 pe = sorted_pe[p];
                px = pe.x;
                a  = __uint_as_float(pe.y) / denom[px >> 15];
            }
            int m = (int)(px & 0x7FFFu);
            mets[tid] = (m < N_MET) ? m : 0;     // pad-safe
            rxns[tid] = (int)(px >> 15);
            als[tid]  = a;
        }
        __syncthreads();                          // (1) meta ready

        const unsigned short* arow = feats_bf + (size_t)mets[wave*16 + erow] * D;
        f32x4 acc[8];
        #pragma unroll
        for (int cf = 0; cf < 8; ++cf) acc[cf] = (f32x4){0.f,0.f,0.f,0.f};
        #pragma unroll
        for (int ks = 0; ks < 4; ++ks){
            short8 a = *(const short8*)(arow + ks*32 + kgrp*8);
            #pragma unroll
            for (int cf = 0; cf < 8; ++cf){
                short8 b = *(const short8*)&Wts[(cf*16 + erow)*136 + ks*32 + kgrp*8];
                acc[cf] = __builtin_amdgcn_mfma_f32_16x16x32_bf16(a, b, acc[cf], 0, 0, 0);
            }
        }
        // stage alpha*relu(t+bt) for all 128 edges (all waves active)
        #pragma unroll
        for (int cf = 0; cf < 8; ++cf){
            #pragma unroll
            for (int r = 0; r < 4; ++r){
                int el = wave*16 + kgrp*4 + r;
                Ls[el*132 + cf*16 + erow] = als[el] * fmaxf(acc[cf][r] + btc[cf], 0.f);
            }
        }
        __syncthreads();                          // (2) staging ready

        if (tid < 128){                           // per-col tile-wide segmented reduce
            const int col = tid;
            int   cur = rxns[0];
            int   i0  = 0;
            float s   = 0.f;
            #pragma unroll 4
            for (int i = 0; i < 128; ++i){
                int r = rxns[i];
                if (r != cur){
                    if (cur < N_RXN){
                        if (i0 > 0) Z[(size_t)cur*D + col] = s;           // interior: i0>0 && ends<127
                        else        atomicAdd(&Z[(size_t)cur*D + col], s);
                    }
                    s = 0.f; cur = r; i0 = i;
                }
                s += Ls[i*132 + col];
            }
            if (cur < N_RXN) atomicAdd(&Z[(size_t)cur*D + col], s);       // touches 127: boundary
        }
        __syncthreads();                          // (3) protect Ls/meta for next tile
    }
}

extern "C" void kernel_launch(void* const* d_in, const int* in_sizes, int n_in,
                              void* d_out, int out_size, void* d_ws, size_t ws_size,
                              hipStream_t stream)
{
    const float* feats = (const float*)d_in[0];
    const int*   he    = (const int*)d_in[1];
    const float* W1    = (const float*)d_in[2];
    const float* b1    = (const float*)d_in[3];
    const float* W2    = (const float*)d_in[4];
    const float* b2    = (const float*)d_in[5];
    const float* Wt    = (const float*)d_in[6];
    const float* bt    = (const float*)d_in[7];
    float* Z = (float*)d_out;

    char* ws = (char*)d_ws;
    size_t off = 0;
    auto alloc = [&](size_t bytes)->char*{
        char* p = ws + off;
        off += (bytes + 255) & ~(size_t)255;
        return p;
    };
    unsigned short* feats_bf = (unsigned short*)alloc((size_t)N_MET*D*2);
    unsigned short* WtT_bf   = (unsigned short*)alloc((size_t)D*D*2);
    unsigned short* W1T_bf   = (unsigned short*)alloc((size_t)D*DH*2);
    float*    gate      = (float*)   alloc((size_t)NEDGE*4);
    char*     zero3     =            alloc((size_t)N_RXN*12);   // count | gmaxkey | denom
    int*      count     = (int*)      zero3;
    unsigned* gmaxkey   = (unsigned*)(zero3 + (size_t)N_RXN*4);
    float*    denom     = (float*)   (zero3 + (size_t)N_RXN*8);
    int*      offsets   = (int*)     alloc((size_t)(N_RXN+1)*4);
    int*      cursor    = (int*)     alloc((size_t)N_RXN*4);
    uint2*    sorted_pe = (uint2*)   alloc((size_t)NEDGE*8);
    int*      flag      = (int*)     alloc(64);

    hipMemsetAsync(zero3, 0, (size_t)N_RXN*12, stream);
    hipMemsetAsync(d_out, 0, (size_t)out_size*4, stream);

    cvt_all_kernel<<<NB_F + NB_WT + NB_W1 + 1, 256, 0, stream>>>(
        feats, Wt, W1, (const unsigned*)he, feats_bf, WtT_bf, W1T_bf, flag);
    gate_kernel<<<1024, 512, 0, stream>>>(feats_bf, he, W1T_bf, b1, W2, b2,
                                          gate, count, gmaxkey, flag);
    scan_kernel<<<1, 1024, 0, stream>>>(count, offsets, cursor);
    reorder_kernel<<<(NEDGE + 255)/256, 256, 0, stream>>>(he, gate, gmaxkey, cursor,
                                                          sorted_pe, denom, flag);
    scatter_kernel<<<256, 512, 0, stream>>>(feats_bf, sorted_pe, denom, WtT_bf, bt, Z);
}

// Round 8
// 418.973 us; speedup vs baseline: 1.5633x; 1.5633x over previous
//
#include <hip/hip_runtime.h>
#include <hip/hip_bf16.h>
#include <math.h>

#define N_MET 20000
#define N_RXN 50000
#define NEDGE 1000000
#define D 128
#define DH 64

typedef __attribute__((ext_vector_type(8))) short short8;   // 8 bf16 raw bits
typedef __attribute__((ext_vector_type(4))) float f32x4;

__device__ __forceinline__ unsigned short f2bf(float x){
    __hip_bfloat16 b = __float2bfloat16(x);
    return *reinterpret_cast<unsigned short*>(&b);
}
__device__ __forceinline__ float bf2f(unsigned short u){
    unsigned v = ((unsigned)u) << 16;
    return __uint_as_float(v);
}
// monotone float<->uint key for atomicMax on floats (key 0 < any finite float's key)
__device__ __forceinline__ unsigned fkey(float x){
    unsigned u = __float_as_uint(x);
    return (u & 0x80000000u) ? ~u : (u | 0x80000000u);
}
__device__ __forceinline__ float fkey_inv(unsigned k){
    unsigned u = (k & 0x80000000u) ? (k ^ 0x80000000u) : ~k;
    return __uint_as_float(u);
}

// ---- fused converts + int64/int32 layout detect ----
#define NB_F ((N_MET*D/4 + 255)/256)   // 2500
#define NB_WT ((D*D + 255)/256)        // 64
#define NB_W1 ((D*DH + 255)/256)       // 32
__global__ __launch_bounds__(256) void cvt_all_kernel(
    const float* __restrict__ feats, const float* __restrict__ Wt,
    const float* __restrict__ W1, const unsigned* __restrict__ he,
    unsigned short* __restrict__ feats_bf, unsigned short* __restrict__ WtT_bf,
    unsigned short* __restrict__ W1T_bf, int* __restrict__ flag)
{
    int b = blockIdx.x;
    if (b < NB_F){
        int i = b*256 + threadIdx.x;
        if (i < N_MET*D/4){
            float4 v = ((const float4*)feats)[i];
            ushort4 o;
            o.x = f2bf(v.x); o.y = f2bf(v.y); o.z = f2bf(v.z); o.w = f2bf(v.w);
            ((ushort4*)feats_bf)[i] = o;
        }
    } else if (b < NB_F + NB_WT){
        int i = (b - NB_F)*256 + threadIdx.x;         // WtT[c*D + k] = Wt[k*D + c]
        if (i < D*D){ int c = i >> 7, k = i & 127; WtT_bf[i] = f2bf(Wt[k*D + c]); }
    } else if (b < NB_F + NB_WT + NB_W1){
        int i = (b - NB_F - NB_WT)*256 + threadIdx.x; // W1T[c*D + k] = W1[k*DH + c]
        if (i < DH*D){ int c = i >> 7, k = i & 127; W1T_bf[i] = f2bf(W1[k*DH + c]); }
    } else {
        if (threadIdx.x == 0){
            int is64 = 1;
            for (int i = 0; i < 64; ++i)
                if (he[2*i + 1] != 0u){ is64 = 0; break; }
            *flag = is64;
        }
    }
}

// ---- Kernel 1: per-METABOLITE gate key + transform table via MFMA ----
// 157 blocks x 512 threads; rows = metabolites. gkey_m[m] = fkey(gate(m));
// T_bf[m][c] = bf16(relu(Wt^T f_m + bt)[c]).
#define NMTILE ((N_MET + 127) >> 7)   // 157
__global__ __launch_bounds__(512) void met_nn_kernel(
    const unsigned short* __restrict__ feats_bf,
    const unsigned short* __restrict__ W1T_bf, const float* __restrict__ b1,
    const float* __restrict__ W2, const float* __restrict__ b2,
    const unsigned short* __restrict__ WtT_bf, const float* __restrict__ bt,
    unsigned* __restrict__ gkey_m, unsigned short* __restrict__ T_bf)
{
    __shared__ __align__(16) unsigned short Fs[128*136];
    __shared__ __align__(16) unsigned short W1s[64*136];
    __shared__ __align__(16) unsigned short Wts[128*136];

    const int tid = threadIdx.x;
    const int base = blockIdx.x * 128;

    for (int i = tid; i < 64*16; i += 512){
        int c = i >> 4, ch = i & 15;
        *(short8*)&W1s[c*136 + ch*8] = *(const short8*)&W1T_bf[c*128 + ch*8];
    }
    for (int i = tid; i < 128*16; i += 512){
        int c = i >> 4, ch = i & 15;
        *(short8*)&Wts[c*136 + ch*8] = *(const short8*)&WtT_bf[c*128 + ch*8];
    }
    {   // stage feats rows base..base+127 (clamped)
        int row = tid >> 2, q = tid & 3;
        int m = base + row; if (m >= N_MET) m = N_MET - 1;
        const unsigned short* src = feats_bf + (size_t)m * D;
        unsigned short* dst = &Fs[row*136];
        #pragma unroll
        for (int it = 0; it < 4; ++it){
            int k = q*8 + it*32;
            *(short8*)(dst + k) = *(const short8*)(src + k);
        }
    }
    __syncthreads();

    const int lane = tid & 63;
    const int wave = tid >> 6;
    const int erow = lane & 15;
    const int kgrp = lane >> 4;

    f32x4 acc1[4], acc2[8];
    #pragma unroll
    for (int cf = 0; cf < 4; ++cf) acc1[cf] = (f32x4){0.f,0.f,0.f,0.f};
    #pragma unroll
    for (int cf = 0; cf < 8; ++cf) acc2[cf] = (f32x4){0.f,0.f,0.f,0.f};

    #pragma unroll
    for (int ks = 0; ks < 4; ++ks){
        short8 a = *(const short8*)&Fs[(wave*16 + erow)*136 + ks*32 + kgrp*8];
        #pragma unroll
        for (int cf = 0; cf < 4; ++cf){
            short8 b = *(const short8*)&W1s[(cf*16 + erow)*136 + ks*32 + kgrp*8];
            acc1[cf] = __builtin_amdgcn_mfma_f32_16x16x32_bf16(a, b, acc1[cf], 0, 0, 0);
        }
        #pragma unroll
        for (int cf = 0; cf < 8; ++cf){
            short8 b = *(const short8*)&Wts[(cf*16 + erow)*136 + ks*32 + kgrp*8];
            acc2[cf] = __builtin_amdgcn_mfma_f32_16x16x32_bf16(a, b, acc2[cf], 0, 0, 0);
        }
    }

    // gate epilogue
    float p[4] = {0.f,0.f,0.f,0.f};
    #pragma unroll
    for (int cf = 0; cf < 4; ++cf){
        int c = cf*16 + erow;
        float b1c = b1[c], w2c = W2[c];
        #pragma unroll
        for (int r = 0; r < 4; ++r)
            p[r] += fmaxf(acc1[cf][r] + b1c, 0.f) * w2c;
    }
    #pragma unroll
    for (int off = 1; off < 16; off <<= 1){
        #pragma unroll
        for (int r = 0; r < 4; ++r) p[r] += __shfl_xor(p[r], off);
    }
    if (erow == 0){
        float b2v = b2[0];
        #pragma unroll
        for (int r = 0; r < 4; ++r){
            int m = base + wave*16 + kgrp*4 + r;
            if (m < N_MET) gkey_m[m] = fkey(p[r] + b2v);
        }
    }
    // T epilogue: row = base + wave*16 + kgrp*4 + r, col = cf*16 + erow
    #pragma unroll
    for (int cf = 0; cf < 8; ++cf){
        int c = cf*16 + erow;
        float btc = bt[c];
        #pragma unroll
        for (int r = 0; r < 4; ++r){
            int m = base + wave*16 + kgrp*4 + r;
            if (m < N_MET)
                T_bf[(size_t)m*D + c] = f2bf(fmaxf(acc2[cf][r] + btc, 0.f));
        }
    }
}

// ---- Kernel 2: per-edge histogram + gmax (uint keys) + pack write ----
__global__ __launch_bounds__(256) void edge_hist_kernel(
    const int* __restrict__ he, const unsigned* __restrict__ gkey_m,
    int* __restrict__ count, unsigned* __restrict__ gmaxkey,
    unsigned* __restrict__ pack_he, const int* __restrict__ flag)
{
    int e = blockIdx.x*256 + threadIdx.x;
    if (e >= NEDGE) return;
    int stride = (*flag) ? 2 : 1;
    int m = he[(size_t)e * stride];
    int r = he[(size_t)(NEDGE + e) * stride];
    pack_he[e] = ((unsigned)r << 15) | (unsigned)m;
    atomicAdd(&count[r], 1);
    atomicMax(&gmaxkey[r], gkey_m[m]);
}

// ---- Kernel 3: scan via wave shfl -> offsets, cursor ----
__global__ __launch_bounds__(1024) void scan_kernel(
    const int* __restrict__ count, int* __restrict__ offsets, int* __restrict__ cursor)
{
    __shared__ int wsum[16];
    __shared__ int sbase;
    const int tid = threadIdx.x, lane = tid & 63, wid = tid >> 6;
    if (tid == 0) sbase = 0;
    __syncthreads();
    for (int start = 0; start < N_RXN; start += 1024){
        int idx = start + tid;
        int v = (idx < N_RXN) ? count[idx] : 0;
        int x = v;
        #pragma unroll
        for (int off = 1; off < 64; off <<= 1){
            int t = __shfl_up(x, off);
            if (lane >= off) x += t;
        }
        if (lane == 63) wsum[wid] = x;
        __syncthreads();
        if (wid == 0){
            int s = (lane < 16) ? wsum[lane] : 0;
            #pragma unroll
            for (int off = 1; off < 16; off <<= 1){
                int t = __shfl_up(s, off);
                if (lane >= off) s += t;
            }
            if (lane < 16) wsum[lane] = s;
        }
        __syncthreads();
        int wbase = (wid == 0) ? 0 : wsum[wid-1];
        int excl = sbase + wbase + x - v;
        if (idx < N_RXN){ offsets[idx] = excl; cursor[idx] = excl; }
        __syncthreads();
        if (tid == 0) sbase += wsum[15];
        __syncthreads();
    }
    if (tid == 0) offsets[N_RXN] = sbase;
}

// ---- Kernel 4: counting-sort reorder + exp + denom ----
__global__ __launch_bounds__(256) void reorder_kernel(
    const unsigned* __restrict__ pack_he, const unsigned* __restrict__ gkey_m,
    const unsigned* __restrict__ gmaxkey, int* __restrict__ cursor,
    uint2* __restrict__ sorted_pe, float* __restrict__ denom)
{
    int e = blockIdx.x*256 + threadIdx.x;
    if (e >= NEDGE) return;
    unsigned pk = pack_he[e];
    int m = (int)(pk & 0x7FFFu);
    int r = (int)(pk >> 15);
    float g  = fkey_inv(gkey_m[m]);
    float ex = expf(g - fkey_inv(gmaxkey[r]));
    int pos = atomicAdd(&cursor[r], 1);
    uint2 pe; pe.x = pk; pe.y = __float_as_uint(ex);
    sorted_pe[pos] = pe;
    atomicAdd(&denom[r], ex);
}

// ---- Kernel 5: gather T rows + weighted segmented sum into Z ----
// 128 sorted edges per block, 512 threads: col = tid&127, subsegment = tid>>7 (32 edges).
__global__ __launch_bounds__(512) void zsum_kernel(
    const uint2* __restrict__ sorted_pe, const float* __restrict__ denom,
    const unsigned short* __restrict__ T_bf, float* __restrict__ Z)
{
    __shared__ unsigned pks[128];
    __shared__ float    als[128];

    const int tid = threadIdx.x;
    const long base = (long)blockIdx.x * 128;

    if (tid < 128){
        long p = base + tid;
        unsigned pk = 0xFFFFFFFFu; float a = 0.f;
        if (p < NEDGE){
            uint2 pe = sorted_pe[p];
            pk = pe.x;
            a  = __uint_as_float(pe.y) / denom[pk >> 15];
        }
        pks[tid] = pk;
        als[tid] = a;
    }
    __syncthreads();

    const int col = tid & 127;
    const int e0  = (tid >> 7) * 32;
    unsigned cur = pks[e0] >> 15;
    float s = 0.f;
    #pragma unroll 4
    for (int i = 0; i < 32; ++i){
        unsigned pk = pks[e0 + i];
        unsigned r  = pk >> 15;
        if (r != cur){
            if (cur < N_RXN) atomicAdd(&Z[(size_t)cur*D + col], s);
            s = 0.f; cur = r;
        }
        s += als[e0 + i] * bf2f(T_bf[(size_t)(pk & 0x7FFFu)*D + col]);
    }
    if (cur < N_RXN) atomicAdd(&Z[(size_t)cur*D + col], s);
}

extern "C" void kernel_launch(void* const* d_in, const int* in_sizes, int n_in,
                              void* d_out, int out_size, void* d_ws, size_t ws_size,
                              hipStream_t stream)
{
    const float* feats = (const float*)d_in[0];
    const int*   he    = (const int*)d_in[1];
    const float* W1    = (const float*)d_in[2];
    const float* b1    = (const float*)d_in[3];
    const float* W2    = (const float*)d_in[4];
    const float* b2    = (const float*)d_in[5];
    const float* Wt    = (const float*)d_in[6];
    const float* bt    = (const float*)d_in[7];
    float* Z = (float*)d_out;

    char* ws = (char*)d_ws;
    size_t off = 0;
    auto alloc = [&](size_t bytes)->char*{
        char* p = ws + off;
        off += (bytes + 255) & ~(size_t)255;
        return p;
    };
    unsigned short* feats_bf = (unsigned short*)alloc((size_t)N_MET*D*2);  // 5.12 MB
    unsigned short* WtT_bf   = (unsigned short*)alloc((size_t)D*D*2);
    unsigned short* W1T_bf   = (unsigned short*)alloc((size_t)D*DH*2);
    unsigned short* T_bf     = (unsigned short*)alloc((size_t)N_MET*D*2);  // 5.12 MB
    unsigned* gkey_m    = (unsigned*)alloc((size_t)N_MET*4);
    char*     zero3     =            alloc((size_t)N_RXN*12);   // count | gmaxkey | denom
    int*      count     = (int*)      zero3;
    unsigned* gmaxkey   = (unsigned*)(zero3 + (size_t)N_RXN*4);
    float*    denom     = (float*)   (zero3 + (size_t)N_RXN*8);
    int*      offsets   = (int*)     alloc((size_t)(N_RXN+1)*4);
    int*      cursor    = (int*)     alloc((size_t)N_RXN*4);
    uint2*    sorted_pe = (uint2*)   alloc((size_t)NEDGE*8);    // 8 MB
    int*      flag      = (int*)     alloc(64);
    // pack_he aliases feats_bf: feats_bf is dead after met_nn_kernel,
    // pack_he is first written by edge_hist_kernel (later on same stream).
    unsigned* pack_he   = (unsigned*)feats_bf;                  // 4 MB <= 5.12 MB

    hipMemsetAsync(zero3, 0, (size_t)N_RXN*12, stream);
    hipMemsetAsync(d_out, 0, (size_t)out_size*4, stream);

    cvt_all_kernel<<<NB_F + NB_WT + NB_W1 + 1, 256, 0, stream>>>(
        feats, Wt, W1, (const unsigned*)he, feats_bf, WtT_bf, W1T_bf, flag);
    met_nn_kernel<<<NMTILE, 512, 0, stream>>>(feats_bf, W1T_bf, b1, W2, b2,
                                              WtT_bf, bt, gkey_m, T_bf);
    edge_hist_kernel<<<(NEDGE + 255)/256, 256, 0, stream>>>(he, gkey_m, count,
                                                            gmaxkey, pack_he, flag);
    scan_kernel<<<1, 1024, 0, stream>>>(count, offsets, cursor);
    reorder_kernel<<<(NEDGE + 255)/256, 256, 0, stream>>>(pack_he, gkey_m, gmaxkey,
                                                          cursor, sorted_pe, denom);
    zsum_kernel<<<(NEDGE + 127)/128, 512, 0, stream>>>(sorted_pe, denom, T_bf, Z);
}

// Round 9
// 304.187 us; speedup vs baseline: 2.1532x; 1.3774x over previous
//
#include <hip/hip_runtime.h>
#include <hip/hip_bf16.h>
#include <math.h>

#define N_MET 20000
#define N_RXN 50000
#define NEDGE 1000000
#define D 128
#define DH 64

typedef __attribute__((ext_vector_type(8))) short short8;   // 8 bf16 raw bits
typedef __attribute__((ext_vector_type(4))) float f32x4;

__device__ __forceinline__ unsigned short f2bf(float x){
    __hip_bfloat16 b = __float2bfloat16(x);
    return *reinterpret_cast<unsigned short*>(&b);
}
__device__ __forceinline__ float bf2f_lo(unsigned u){ return __uint_as_float(u << 16); }
__device__ __forceinline__ float bf2f_hi(unsigned u){ return __uint_as_float(u & 0xFFFF0000u); }

// ---- fused converts + int64/int32 layout detect ----
#define NB_F ((N_MET*D/4 + 255)/256)   // 2500
#define NB_WT ((D*D + 255)/256)        // 64
#define NB_W1 ((D*DH + 255)/256)       // 32
__global__ __launch_bounds__(256) void cvt_all_kernel(
    const float* __restrict__ feats, const float* __restrict__ Wt,
    const float* __restrict__ W1, const unsigned* __restrict__ he,
    unsigned short* __restrict__ feats_bf, unsigned short* __restrict__ WtT_bf,
    unsigned short* __restrict__ W1T_bf, int* __restrict__ flag)
{
    int b = blockIdx.x;
    if (b < NB_F){
        int i = b*256 + threadIdx.x;
        if (i < N_MET*D/4){
            float4 v = ((const float4*)feats)[i];
            ushort4 o;
            o.x = f2bf(v.x); o.y = f2bf(v.y); o.z = f2bf(v.z); o.w = f2bf(v.w);
            ((ushort4*)feats_bf)[i] = o;
        }
    } else if (b < NB_F + NB_WT){
        int i = (b - NB_F)*256 + threadIdx.x;         // WtT[c*D + k] = Wt[k*D + c]
        if (i < D*D){ int c = i >> 7, k = i & 127; WtT_bf[i] = f2bf(Wt[k*D + c]); }
    } else if (b < NB_F + NB_WT + NB_W1){
        int i = (b - NB_F - NB_WT)*256 + threadIdx.x; // W1T[c*D + k] = W1[k*DH + c]
        if (i < DH*D){ int c = i >> 7, k = i & 127; W1T_bf[i] = f2bf(W1[k*DH + c]); }
    } else {
        if (threadIdx.x == 0){
            int is64 = 1;
            for (int i = 0; i < 64; ++i)
                if (he[2*i + 1] != 0u){ is64 = 0; break; }
            *flag = is64;
        }
    }
}

// ---- Kernel 1: per-METABOLITE exp(gate) + transform table via MFMA ----
// eg_m[m] = exp(gate(m)); T_bf[m][c] = bf16(relu(Wt^T f_m + bt)[c]).
// (No max-subtraction: softmax is shift-invariant; gate here is O(1) so exp is safe.)
#define NMTILE ((N_MET + 127) >> 7)   // 157
__global__ __launch_bounds__(512) void met_nn_kernel(
    const unsigned short* __restrict__ feats_bf,
    const unsigned short* __restrict__ W1T_bf, const float* __restrict__ b1,
    const float* __restrict__ W2, const float* __restrict__ b2,
    const unsigned short* __restrict__ WtT_bf, const float* __restrict__ bt,
    float* __restrict__ eg_m, unsigned short* __restrict__ T_bf)
{
    __shared__ __align__(16) unsigned short Fs[128*136];
    __shared__ __align__(16) unsigned short W1s[64*136];
    __shared__ __align__(16) unsigned short Wts[128*136];

    const int tid = threadIdx.x;
    const int base = blockIdx.x * 128;

    for (int i = tid; i < 64*16; i += 512){
        int c = i >> 4, ch = i & 15;
        *(short8*)&W1s[c*136 + ch*8] = *(const short8*)&W1T_bf[c*128 + ch*8];
    }
    for (int i = tid; i < 128*16; i += 512){
        int c = i >> 4, ch = i & 15;
        *(short8*)&Wts[c*136 + ch*8] = *(const short8*)&WtT_bf[c*128 + ch*8];
    }
    {   // stage feats rows base..base+127 (clamped)
        int row = tid >> 2, q = tid & 3;
        int m = base + row; if (m >= N_MET) m = N_MET - 1;
        const unsigned short* src = feats_bf + (size_t)m * D;
        unsigned short* dst = &Fs[row*136];
        #pragma unroll
        for (int it = 0; it < 4; ++it){
            int k = q*8 + it*32;
            *(short8*)(dst + k) = *(const short8*)(src + k);
        }
    }
    __syncthreads();

    const int lane = tid & 63;
    const int wave = tid >> 6;
    const int erow = lane & 15;
    const int kgrp = lane >> 4;

    f32x4 acc1[4], acc2[8];
    #pragma unroll
    for (int cf = 0; cf < 4; ++cf) acc1[cf] = (f32x4){0.f,0.f,0.f,0.f};
    #pragma unroll
    for (int cf = 0; cf < 8; ++cf) acc2[cf] = (f32x4){0.f,0.f,0.f,0.f};

    #pragma unroll
    for (int ks = 0; ks < 4; ++ks){
        short8 a = *(const short8*)&Fs[(wave*16 + erow)*136 + ks*32 + kgrp*8];
        #pragma unroll
        for (int cf = 0; cf < 4; ++cf){
            short8 b = *(const short8*)&W1s[(cf*16 + erow)*136 + ks*32 + kgrp*8];
            acc1[cf] = __builtin_amdgcn_mfma_f32_16x16x32_bf16(a, b, acc1[cf], 0, 0, 0);
        }
        #pragma unroll
        for (int cf = 0; cf < 8; ++cf){
            short8 b = *(const short8*)&Wts[(cf*16 + erow)*136 + ks*32 + kgrp*8];
            acc2[cf] = __builtin_amdgcn_mfma_f32_16x16x32_bf16(a, b, acc2[cf], 0, 0, 0);
        }
    }

    // gate epilogue -> exp(gate)
    float p[4] = {0.f,0.f,0.f,0.f};
    #pragma unroll
    for (int cf = 0; cf < 4; ++cf){
        int c = cf*16 + erow;
        float b1c = b1[c], w2c = W2[c];
        #pragma unroll
        for (int r = 0; r < 4; ++r)
            p[r] += fmaxf(acc1[cf][r] + b1c, 0.f) * w2c;
    }
    #pragma unroll
    for (int off = 1; off < 16; off <<= 1){
        #pragma unroll
        for (int r = 0; r < 4; ++r) p[r] += __shfl_xor(p[r], off);
    }
    if (erow == 0){
        float b2v = b2[0];
        #pragma unroll
        for (int r = 0; r < 4; ++r){
            int m = base + wave*16 + kgrp*4 + r;
            if (m < N_MET) eg_m[m] = expf(p[r] + b2v);
        }
    }
    // T epilogue
    #pragma unroll
    for (int cf = 0; cf < 8; ++cf){
        int c = cf*16 + erow;
        float btc = bt[c];
        #pragma unroll
        for (int r = 0; r < 4; ++r){
            int m = base + wave*16 + kgrp*4 + r;
            if (m < N_MET)
                T_bf[(size_t)m*D + c] = f2bf(fmaxf(acc2[cf][r] + btc, 0.f));
        }
    }
}

// ---- Kernel 2: per-edge pack + count histogram ----
__global__ __launch_bounds__(256) void edge_hist_kernel(
    const int* __restrict__ he, int* __restrict__ count,
    unsigned* __restrict__ pack_he, const int* __restrict__ flag)
{
    int e = blockIdx.x*256 + threadIdx.x;
    if (e >= NEDGE) return;
    int stride = (*flag) ? 2 : 1;
    int m = he[(size_t)e * stride];
    int r = he[(size_t)(NEDGE + e) * stride];
    pack_he[e] = ((unsigned)r << 15) | (unsigned)m;
    atomicAdd(&count[r], 1);
}

// ---- Kernel 3: scan via wave shfl -> offsets, cursor ----
__global__ __launch_bounds__(1024) void scan_kernel(
    const int* __restrict__ count, int* __restrict__ offsets, int* __restrict__ cursor)
{
    __shared__ int wsum[16];
    __shared__ int sbase;
    const int tid = threadIdx.x, lane = tid & 63, wid = tid >> 6;
    if (tid == 0) sbase = 0;
    __syncthreads();
    for (int start = 0; start < N_RXN; start += 1024){
        int idx = start + tid;
        int v = (idx < N_RXN) ? count[idx] : 0;
        int x = v;
        #pragma unroll
        for (int off = 1; off < 64; off <<= 1){
            int t = __shfl_up(x, off);
            if (lane >= off) x += t;
        }
        if (lane == 63) wsum[wid] = x;
        __syncthreads();
        if (wid == 0){
            int s = (lane < 16) ? wsum[lane] : 0;
            #pragma unroll
            for (int off = 1; off < 16; off <<= 1){
                int t = __shfl_up(s, off);
                if (lane >= off) s += t;
            }
            if (lane < 16) wsum[lane] = s;
        }
        __syncthreads();
        int wbase = (wid == 0) ? 0 : wsum[wid-1];
        int excl = sbase + wbase + x - v;
        if (idx < N_RXN){ offsets[idx] = excl; cursor[idx] = excl; }
        __syncthreads();
        if (tid == 0) sbase += wsum[15];
        __syncthreads();
    }
    if (tid == 0) offsets[N_RXN] = sbase;
}

// ---- Kernel 4: counting-sort reorder: scatter ONLY ushort met-id (2B) ----
__global__ __launch_bounds__(256) void reorder_kernel(
    const unsigned* __restrict__ pack_he, int* __restrict__ cursor,
    unsigned short* __restrict__ sorted_met)
{
    int e = blockIdx.x*256 + threadIdx.x;
    if (e >= NEDGE) return;
    unsigned pk = pack_he[e];
    int r = (int)(pk >> 15);
    int pos = atomicAdd(&cursor[r], 1);
    sorted_met[pos] = (unsigned short)(pk & 0x7FFFu);
}

// ---- Kernel 5: one wave per reaction: denom + weighted sum, no atomics ----
// lane owns cols (2*lane, 2*lane+1) via packed 4B T loads; float2 store.
__global__ __launch_bounds__(256) void zsum_kernel(
    const int* __restrict__ offsets, const unsigned short* __restrict__ sorted_met,
    const float* __restrict__ eg_m, const unsigned* __restrict__ T2,  // T_bf as uint pairs
    float* __restrict__ Z)
{
    const int r = blockIdx.x*4 + (threadIdx.x >> 6);
    if (r >= N_RXN) return;
    const int lane = threadIdx.x & 63;
    const int s = offsets[r], epos = offsets[r+1];

    float2 acc = {0.f, 0.f};
    if (epos > s){
        // pass 1: denom = sum of eg_m over edges (lane-parallel + reduce)
        float dsum = 0.f;
        for (int c0 = s; c0 < epos; c0 += 64){
            int i = c0 + lane;
            if (i < epos) dsum += eg_m[sorted_met[i]];
        }
        #pragma unroll
        for (int off = 1; off < 64; off <<= 1) dsum += __shfl_xor(dsum, off);
        const float inv = 1.0f / dsum;

        // pass 2: accumulate alpha * T rows
        for (int c0 = s; c0 < epos; c0 += 64){
            int i = c0 + lane;
            int m = 0; float a = 0.f;
            if (i < epos){ m = sorted_met[i]; a = eg_m[m] * inv; }
            int cnt = epos - c0; if (cnt > 64) cnt = 64;
            for (int j = 0; j < cnt; ++j){
                float aj = __shfl(a, j);
                int   mj = __shfl(m, j);
                unsigned u = T2[(size_t)mj*64 + lane];     // cols 2*lane, 2*lane+1
                acc.x += aj * bf2f_lo(u);
                acc.y += aj * bf2f_hi(u);
            }
        }
    }
    ((float2*)(Z + (size_t)r*D))[lane] = acc;   // exactly-once, covers empty rows too
}

extern "C" void kernel_launch(void* const* d_in, const int* in_sizes, int n_in,
                              void* d_out, int out_size, void* d_ws, size_t ws_size,
                              hipStream_t stream)
{
    const float* feats = (const float*)d_in[0];
    const int*   he    = (const int*)d_in[1];
    const float* W1    = (const float*)d_in[2];
    const float* b1    = (const float*)d_in[3];
    const float* W2    = (const float*)d_in[4];
    const float* b2    = (const float*)d_in[5];
    const float* Wt    = (const float*)d_in[6];
    const float* bt    = (const float*)d_in[7];
    float* Z = (float*)d_out;

    char* ws = (char*)d_ws;
    size_t off = 0;
    auto alloc = [&](size_t bytes)->char*{
        char* p = ws + off;
        off += (bytes + 255) & ~(size_t)255;
        return p;
    };
    unsigned short* feats_bf  = (unsigned short*)alloc((size_t)N_MET*D*2);  // 5.12 MB
    unsigned short* WtT_bf    = (unsigned short*)alloc((size_t)D*D*2);
    unsigned short* W1T_bf    = (unsigned short*)alloc((size_t)D*DH*2);
    unsigned short* T_bf      = (unsigned short*)alloc((size_t)N_MET*D*2);  // 5.12 MB
    float*          eg_m      = (float*)         alloc((size_t)N_MET*4);
    int*            count     = (int*)           alloc((size_t)N_RXN*4);
    int*            offsets   = (int*)           alloc((size_t)(N_RXN+1)*4);
    int*            cursor    = (int*)           alloc((size_t)N_RXN*4);
    unsigned short* sorted_met= (unsigned short*)alloc((size_t)NEDGE*2);    // 2 MB
    int*            flag      = (int*)           alloc(64);
    // pack_he aliases feats_bf (dead after met_nn; written by edge_hist later on stream)
    unsigned*       pack_he   = (unsigned*)feats_bf;                        // 4 MB <= 5.12 MB

    hipMemsetAsync(count, 0, (size_t)N_RXN*4, stream);

    cvt_all_kernel<<<NB_F + NB_WT + NB_W1 + 1, 256, 0, stream>>>(
        feats, Wt, W1, (const unsigned*)he, feats_bf, WtT_bf, W1T_bf, flag);
    met_nn_kernel<<<NMTILE, 512, 0, stream>>>(feats_bf, W1T_bf, b1, W2, b2,
                                              WtT_bf, bt, eg_m, T_bf);
    edge_hist_kernel<<<(NEDGE + 255)/256, 256, 0, stream>>>(he, count, pack_he, flag);
    scan_kernel<<<1, 1024, 0, stream>>>(count, offsets, cursor);
    reorder_kernel<<<(NEDGE + 255)/256, 256, 0, stream>>>(pack_he, cursor, sorted_met);
    zsum_kernel<<<(N_RXN + 3)/4, 256, 0, stream>>>(offsets, sorted_met, eg_m,
                                                   (const unsigned*)T_bf, Z);
}